// Round 14
// baseline (2730.431 us; speedup 1.0000x reference)
//
#include <hip/hip_runtime.h>
#include <hip/hip_bf16.h>
#include <hip/hip_fp8.h>

// BDLOTreeLSTM on MI355X — round 14: 8-wave seq (512 thr, waves_per_eu(2,2) ->
// 256 VGPR/wave). Wave owns N=128 ((g,p) layout from R5). g=0 B-tiles persisted
// in registers (64 VGPR, fits now); g=1..3 streamed with ~3x deeper load window.
// fp8 core/LDS layout = R8 (verified). enc/dec/packs: verified, untouched.

constexpr int Hd    = 256;
constexpr int NBv   = 3;
constexpr int NVv   = 64;
constexpr int BATCH = 512;
constexpr long long NROWS = (long long)BATCH * NBv * NVv;   // 98304
constexpr int CLEN = 40;
constexpr int CI0 = 16, CI1 = 48;

typedef __hip_bfloat16 bf16;
typedef unsigned short ushort;
typedef unsigned char u8;
typedef __attribute__((ext_vector_type(8))) short short8;
typedef __attribute__((ext_vector_type(4))) float f32x4;
typedef __attribute__((ext_vector_type(2))) long longx2;

__device__ __forceinline__ float sigf(float x)   { return 1.f / (1.f + __expf(-x)); }
__device__ __forceinline__ float tanh_f(float x) { return 1.f - 2.f / (__expf(2.f * x) + 1.f); }

__device__ __forceinline__ ushort f2bf(float x) {
  unsigned u = __float_as_uint(x);
  return (ushort)((u + 0x7FFFu + ((u >> 16) & 1u)) >> 16);   // RNE
}
__device__ __forceinline__ float bf2f(ushort u) {
  return __uint_as_float(((unsigned)u) << 16);
}
__device__ __forceinline__ u8 f2fp8(float x) {
  __hip_fp8_e4m3 q(x);
  return (u8)q.__x;
}

// Per-step barrier (R13-verified, == syncthreads perf; keeps stores in flight)
#define STEPSYNC() { \
    asm volatile("s_waitcnt lgkmcnt(0)" ::: "memory"); \
    __builtin_amdgcn_s_barrier(); }

// ================= fp8 weight packing (round-8 verified) ======================
__global__ __launch_bounds__(256) void pack_bu8_kernel(
    const float* __restrict__ W_iou, const float* __restrict__ W_f,
    const float* __restrict__ U_iou, const float* __restrict__ U_f,
    u8* __restrict__ out)   // [512 K][1024 N]: [[W_iou|W_f];[U_iou|U_f]]
{
  int u = blockIdx.x * 256 + threadIdx.x;      // 0..65535
  int s = u & 1, l = (u >> 1) & 63, T = u >> 7;
  int kp = T & 7, nt = T >> 3;
  int ks = kp * 2 + s;
  int k0 = ks * 32 + (l >> 4) * 8;
  int n  = nt * 16 + (l & 15);
  unsigned long long r = 0;
#pragma unroll
  for (int j = 0; j < 8; ++j) {
    int k = k0 + j;
    float v;
    if (k < 256) v = (n < 768) ? W_iou[k * 768 + n] : W_f[k * 256 + (n - 768)];
    else         v = (n < 768) ? U_iou[(k - 256) * 768 + n] : U_f[(k - 256) * 256 + (n - 768)];
    r |= ((unsigned long long)f2fp8(v)) << (8 * j);
  }
  *(unsigned long long*)(out + (size_t)u * 8) = r;
}

__global__ __launch_bounds__(256) void pack_td8_kernel(
    const float* __restrict__ W_ih, const float* __restrict__ W_hh,
    u8* __restrict__ out)   // [512][1024]: [[W_ih];[W_hh]]
{
  int u = blockIdx.x * 256 + threadIdx.x;
  int s = u & 1, l = (u >> 1) & 63, T = u >> 7;
  int kp = T & 7, nt = T >> 3;
  int ks = kp * 2 + s;
  int k0 = ks * 32 + (l >> 4) * 8;
  int n  = nt * 16 + (l & 15);
  unsigned long long r = 0;
#pragma unroll
  for (int j = 0; j < 8; ++j) {
    int k = k0 + j;
    float v = (k < 256) ? W_ih[k * 1024 + n] : W_hh[(k - 256) * 1024 + n];
    r |= ((unsigned long long)f2fp8(v)) << (8 * j);
  }
  *(unsigned long long*)(out + (size_t)u * 8) = r;
}

__global__ __launch_bounds__(256) void pack_wfx8_kernel(
    const float* __restrict__ W_f, u8* __restrict__ out)   // [256][256], NKS=8
{
  int u = blockIdx.x * 256 + threadIdx.x;      // 0..8191
  int s = u & 1, l = (u >> 1) & 63, T = u >> 7;
  int kp = T & 3, nt = T >> 2;
  int ks = kp * 2 + s;
  int k0 = ks * 32 + (l >> 4) * 8;
  int n  = nt * 16 + (l & 15);
  unsigned long long r = 0;
#pragma unroll
  for (int j = 0; j < 8; ++j)
    r |= ((unsigned long long)f2fp8(W_f[(k0 + j) * 256 + n])) << (8 * j);
  *(unsigned long long*)(out + (size_t)u * 8) = r;
}

// ================= bf16 packs for enc/dec (round-7 verified) ==================
__global__ __launch_bounds__(256) void pack_encw2_kernel(
    const float* __restrict__ w2, ushort* __restrict__ out)   // [256][256], NKS=8
{
  int idx = blockIdx.x * 256 + threadIdx.x;
  int j = idx & 7, l = (idx >> 3) & 63, T = idx >> 9;
  int ks = T & 7, nt = T >> 3;
  int k = ks * 32 + (l >> 4) * 8 + j;
  int n = nt * 16 + (l & 15);
  out[idx] = f2bf(w2[k * 256 + n]);
}

__global__ __launch_bounds__(256) void pack_decw1_kernel(
    const float* __restrict__ w1, ushort* __restrict__ out)   // [512][256], NKS=16
{
  int idx = blockIdx.x * 256 + threadIdx.x;
  int j = idx & 7, l = (idx >> 3) & 63, T = idx >> 9;
  int ks = T & 15, nt = T >> 4;
  int k = ks * 32 + (l >> 4) * 8 + j;
  int n = nt * 16 + (l & 15);
  out[idx] = f2bf(w1[k * 256 + n]);
}

__global__ __launch_bounds__(256) void pack_decw2_kernel(
    const float* __restrict__ w2, ushort* __restrict__ out)   // [256][3->16], NKS=8
{
  int idx = blockIdx.x * 256 + threadIdx.x;
  int j = idx & 7, l = (idx >> 3) & 63, T = idx >> 9;
  int ks = T & 7;
  int k = ks * 32 + (l >> 4) * 8 + j;
  int n = l & 15;
  out[idx] = (n < 3) ? f2bf(w2[k * 3 + n]) : (ushort)0;
}

// ================= LDS helpers ================================================
__device__ __forceinline__ short8 ldA16(const ushort* buf, int row, int kbyte) {
  int off = (row * 512 + kbyte) ^ ((row & 7) << 4);
  return *(const short8*)((const char*)buf + off);
}
__device__ __forceinline__ short8 ldA1024(const ushort* buf, int row, int kbyte) {
  int off = (row * 1024 + kbyte) ^ ((row & 7) << 4);
  return *(const short8*)((const char*)buf + off);
}
#define STA(BUF, R, JJ, BITS) { \
    int off_ = ((R) * 512 + (JJ) * 2) ^ (((R) & 7) << 4); \
    (BUF)[off_ >> 1] = (BITS); }
// fp8 A-tile (R8 layout): [rows][256 B], swizzle byte ^ ((row&7)<<3).
#define STA8(BUF, R, JJ, B8) { \
    int off_ = ((R) * 256 + (JJ)) ^ (((R) & 7) << 3); \
    (BUF)[off_] = (B8); }

// ================= encoder (round-7 verified) =================================
__global__ __launch_bounds__(256) void enc_kernel(
    const float* __restrict__ cv, const float* __restrict__ pv,
    const float* __restrict__ hints,
    const float* __restrict__ w1, const float* __restrict__ b1,
    const ushort* __restrict__ w2p, const float* __restrict__ b2,
    ushort* __restrict__ enc)
{
  __shared__ float fs[32][10];
  __shared__ ushort h1L[32 * 256];
  const long long row0 = (long long)blockIdx.x * 32;
  const int tid = threadIdx.x;
  if (tid < 96) {
    int r = tid / 3, c = tid % 3;
    long long row = row0 + r;
    float a = cv[row * 3 + c];
    fs[r][c]     = a;
    fs[r][3 + c] = a - pv[row * 3 + c];
    fs[r][6 + c] = hints[row * 3 + c];
  }
  __syncthreads();
  {
    const int j = tid;
    float wc[9];
#pragma unroll
    for (int i = 0; i < 9; ++i) wc[i] = w1[i * 256 + j];
    const float bb = b1[j];
    for (int r = 0; r < 32; ++r) {
      float a = bb;
#pragma unroll
      for (int i = 0; i < 9; ++i) a += fs[r][i] * wc[i];
      ushort hb = f2bf(fmaxf(a, 0.f));
      STA(h1L, r, j, hb);
    }
  }
  __syncthreads();
  const int lane = tid & 63, w = tid >> 6;
  const int col = lane & 15, krow = lane >> 4, kb = krow * 16;
  const f32x4 zf4 = {0.f, 0.f, 0.f, 0.f};
  f32x4 acc[2][4];
#pragma unroll
  for (int m = 0; m < 2; ++m)
#pragma unroll
    for (int g = 0; g < 4; ++g) acc[m][g] = zf4;
#pragma unroll
  for (int ks = 0; ks < 8; ++ks) {
    short8 A[2];
#pragma unroll
    for (int m = 0; m < 2; ++m) A[m] = ldA16(h1L, m * 16 + col, ks * 64 + kb);
#pragma unroll
    for (int g = 0; g < 4; ++g) {
      short8 b = *(const short8*)(w2p + ((((w * 4 + g) * 8 + ks) * 64 + lane)) * 8);
#pragma unroll
      for (int m = 0; m < 2; ++m)
        acc[m][g] = __builtin_amdgcn_mfma_f32_16x16x32_bf16(A[m], b, acc[m][g], 0, 0, 0);
    }
  }
#pragma unroll
  for (int g = 0; g < 4; ++g) {
    const int jj = (w * 4 + g) * 16 + col;
    const float bb = b2[jj];
#pragma unroll
    for (int m = 0; m < 2; ++m)
#pragma unroll
      for (int q = 0; q < 4; ++q) {
        long long row = row0 + m * 16 + krow * 4 + q;
        enc[row * 256 + jj] = f2bf(acc[m][g][q] + bb);
      }
  }
}

// ================= seq kernel: fp8 GEMMs, 8 waves, g0 persisted ===============
// Wave w owns n-tiles {g*16 + 2w + p : g in 0..3, p in 0..1} (N=128).
// g=0 tiles persisted in Bp[2][8] (constant per weight panel).
template<int MT>
__device__ __forceinline__ void gemm_main8(
    const u8* __restrict__ W, const u8* __restrict__ AxL,
    const u8* __restrict__ AhL, f32x4 (&acc)[MT][4][2],
    const longx2 (&Bp)[2][8], int w, int lane)
{
  const int col = lane & 15;
  const int kb  = (lane >> 4) * 8;
  const int sw  = (col & 7) << 3;
#pragma unroll 4
  for (int kp = 0; kp < 8; ++kp) {
    const u8* Ab = (kp < 4) ? AxL : AhL;
    const int ksl = (kp & 3) * 2;
    long a[MT][2];
#pragma unroll
    for (int m = 0; m < MT; ++m) {
      int base = (m * 16 + col) * 256 + ksl * 32 + kb;
      a[m][0] = *(const long*)(Ab + ((base) ^ sw));
      a[m][1] = *(const long*)(Ab + ((base + 32) ^ sw));
    }
#pragma unroll
    for (int p = 0; p < 2; ++p)
#pragma unroll
      for (int m = 0; m < MT; ++m) {
        acc[m][0][p] = __builtin_amdgcn_mfma_f32_16x16x32_fp8_fp8(a[m][0], Bp[p][kp][0], acc[m][0][p], 0, 0, 0);
        acc[m][0][p] = __builtin_amdgcn_mfma_f32_16x16x32_fp8_fp8(a[m][1], Bp[p][kp][1], acc[m][0][p], 0, 0, 0);
      }
#pragma unroll
    for (int g = 1; g < 4; ++g)
#pragma unroll
      for (int p = 0; p < 2; ++p) {
        longx2 bq = *(const longx2*)(W + ((size_t)(((g * 16 + 2 * w + p) * 8 + kp) * 64 + lane) << 4));
#pragma unroll
        for (int m = 0; m < MT; ++m) {
          acc[m][g][p] = __builtin_amdgcn_mfma_f32_16x16x32_fp8_fp8(a[m][0], bq[0], acc[m][g][p], 0, 0, 0);
          acc[m][g][p] = __builtin_amdgcn_mfma_f32_16x16x32_fp8_fp8(a[m][1], bq[1], acc[m][g][p], 0, 0, 0);
        }
      }
  }
}

__device__ __forceinline__ void gemm_side8(
    const u8* __restrict__ Wbu, const u8* __restrict__ Wfx,
    const u8* __restrict__ Rhb, const u8* __restrict__ AxL,
    f32x4 (&accs)[4][2], f32x4 (&accw)[2], int w, int lane)
{
  const int col = lane & 15;
  const int kb  = (lane >> 4) * 8;
  const int sw  = (col & 7) << 3;
#pragma unroll
  for (int kp = 0; kp < 4; ++kp) {
    const int base = col * 256 + kp * 64 + kb;
    long ar0 = *(const long*)(Rhb + ((base) ^ sw));
    long ar1 = *(const long*)(Rhb + ((base + 32) ^ sw));
#pragma unroll
    for (int g = 0; g < 4; ++g)
#pragma unroll
      for (int p = 0; p < 2; ++p) {
        longx2 bq = *(const longx2*)(Wbu + ((size_t)(((g * 16 + 2 * w + p) * 8 + kp + 4) * 64 + lane) << 4));
        accs[g][p] = __builtin_amdgcn_mfma_f32_16x16x32_fp8_fp8(ar0, bq[0], accs[g][p], 0, 0, 0);
        accs[g][p] = __builtin_amdgcn_mfma_f32_16x16x32_fp8_fp8(ar1, bq[1], accs[g][p], 0, 0, 0);
      }
    long ax0 = *(const long*)(AxL + ((base) ^ sw));
    long ax1 = *(const long*)(AxL + ((base + 32) ^ sw));
#pragma unroll
    for (int p = 0; p < 2; ++p) {
      longx2 bw = *(const longx2*)(Wfx + ((size_t)(((2 * w + p) * 4 + kp) * 64 + lane) << 4));
      accw[p] = __builtin_amdgcn_mfma_f32_16x16x32_fp8_fp8(ax0, bw[0], accw[p], 0, 0, 0);
      accw[p] = __builtin_amdgcn_mfma_f32_16x16x32_fp8_fp8(ax1, bw[1], accw[p], 0, 0, 0);
    }
  }
}

#define ZACC(MT_, A_) { \
  _Pragma("unroll") for (int m_ = 0; m_ < MT_; ++m_) \
  _Pragma("unroll") for (int g_ = 0; g_ < 4; ++g_) \
  _Pragma("unroll") for (int p_ = 0; p_ < 2; ++p_) A_[m_][g_][p_] = zf4; }

__global__ __launch_bounds__(512, 2)
__attribute__((amdgpu_waves_per_eu(2, 2)))     // 2 waves/EU -> 256 VGPR budget
void seq_kernel(
    const ushort* enc,                      // aliases td_h -> no __restrict__
    const u8* __restrict__ Wbu, const u8* __restrict__ Wtd,
    const u8* __restrict__ Wfx,
    const float* __restrict__ b_iou, const float* __restrict__ b_f,
    const float* __restrict__ b_ih,  const float* __restrict__ b_hh,
    ushort* __restrict__ bu_h, ushort* td_h)
{
  __shared__ u8 Axb[2][32 * 256];
  __shared__ u8 Ahb[2][32 * 256];
  __shared__ u8 Rh[2][16 * 256];

  const int tid  = threadIdx.x;
  const int lane = tid & 63;
  const int w    = tid >> 6;        // wave 0..7
  const int b0   = blockIdx.x * 16;
  const int col  = lane & 15;
  const int krow = lane >> 4;
  const f32x4 zf4 = {0.f, 0.f, 0.f, 0.f};

  float bi0[2], bi1[2], bi2[2], bfv[2], bt0[2], bt1[2], bt2[2], bt3[2];
#pragma unroll
  for (int p = 0; p < 2; ++p) {
    int jj = (2 * w + p) * 16 + col;
    bi0[p] = b_iou[jj]; bi1[p] = b_iou[256 + jj]; bi2[p] = b_iou[512 + jj];
    bfv[p] = b_f[jj];
    bt0[p] = b_ih[jj]       + b_hh[jj];
    bt1[p] = b_ih[256 + jj] + b_hh[256 + jj];
    bt2[p] = b_ih[512 + jj] + b_hh[512 + jj];
    bt3[p] = b_ih[768 + jj] + b_hh[768 + jj];
  }

  float c2[2][2][4];                // (m, p, q)
  float rc0[2][4], rc1[2][4];
  float sc0[2][4], sc1[2][4];

  longx2 Bp[2][8];                  // persisted g=0 tiles (nt = 2w+p), per panel
#define LOADBP(W_) { \
    _Pragma("unroll") for (int kp_ = 0; kp_ < 8; ++kp_) \
    _Pragma("unroll") for (int p_ = 0; p_ < 2; ++p_) \
      Bp[p_][kp_] = *(const longx2*)((W_) + ((size_t)(((2 * w + p_) * 8 + kp_) * 64 + lane) << 4)); }

  // staging: 512 threads; 32-row tiles need 2 chunks/thread, 16-row need 1.
#define SLOAD32(V, XV2) { \
    _Pragma("unroll") for (int h_ = 0; h_ < 2; ++h_) { \
      int cid_ = tid + h_ * 512; int rr_ = cid_ >> 5, ch_ = cid_ & 31; \
      int mt_ = rr_ >> 4, br_ = rr_ & 15; \
      long long rowg_ = ((long long)(b0 + br_) * NBv + (mt_ + 1)) * NVv + (V); \
      XV2[h_] = *(const short8*)(enc + rowg_ * 256 + ch_ * 8); } }

#define SWRITE32(DST, XV2) { \
    _Pragma("unroll") for (int h_ = 0; h_ < 2; ++h_) { \
      int cid_ = tid + h_ * 512; int rr_ = cid_ >> 5, ch_ = cid_ & 31; \
      unsigned long long r_ = 0; \
      _Pragma("unroll") for (int e_ = 0; e_ < 8; ++e_) \
        r_ |= ((unsigned long long)f2fp8(bf2f((ushort)XV2[h_][e_]))) << (8 * e_); \
      *(unsigned long long*)((DST) + (((rr_ * 256 + ch_ * 8) ^ ((rr_ & 7) << 3)))) = r_; } }

#define SLOAD16(V, XV) { \
    int rr_ = tid >> 5, ch_ = tid & 31; \
    long long rowg_ = ((long long)(b0 + rr_) * NBv) * NVv + (V); \
    XV = *(const short8*)(enc + rowg_ * 256 + ch_ * 8); }

#define SWRITE16(DST, XV) { \
    int rr_ = tid >> 5, ch_ = tid & 31; \
    unsigned long long r_ = 0; \
    _Pragma("unroll") for (int e_ = 0; e_ < 8; ++e_) \
      r_ |= ((unsigned long long)f2fp8(bf2f((ushort)XV[e_]))) << (8 * e_); \
    *(unsigned long long*)((DST) + (((rr_ * 256 + ch_ * 8) ^ ((rr_ & 7) << 3)))) = r_; }

  // ================= PHASE 1: fused bottom-up chains (v 39..0) ===============
  {
    LOADBP(Wbu);
#pragma unroll
    for (int h_ = 0; h_ < 2; ++h_)
      *(unsigned long long*)(&Ahb[0][(tid + h_ * 512) * 8]) = 0ull;
    short8 xv2[2]; SLOAD32(CLEN - 1, xv2);
#pragma unroll
    for (int m = 0; m < 2; ++m)
#pragma unroll
      for (int p = 0; p < 2; ++p)
#pragma unroll
        for (int q = 0; q < 4; ++q) c2[m][p][q] = 0.f;
    SWRITE32(Axb[0], xv2);
    __syncthreads();
    for (int s = 0; s < CLEN; ++s) {
      const int v = CLEN - 1 - s, pp = s & 1;
      short8 xn2[2];
      if (s < CLEN - 1) SLOAD32(v - 1, xn2);
      f32x4 acc[2][4][2]; ZACC(2, acc);
      gemm_main8<2>(Wbu, Axb[pp], Ahb[pp], acc, Bp, w, lane);
#pragma unroll
      for (int m = 0; m < 2; ++m)
#pragma unroll
        for (int p = 0; p < 2; ++p) {
          const int jj = (2 * w + p) * 16 + col;
#pragma unroll
          for (int q = 0; q < 4; ++q) {
            const int br = krow * 4 + q;
            float I = acc[m][0][p][q] + bi0[p];
            float O = acc[m][1][p][q] + bi1[p];
            float U = acc[m][2][p][q] + bi2[p];
            float F = acc[m][3][p][q] + bfv[p];
            float cn = sigf(I) * tanh_f(U) + sigf(F) * c2[m][p][q];
            float hn = sigf(O) * tanh_f(cn);
            c2[m][p][q] = cn;
            u8 hq = f2fp8(hn);
            STA8(Ahb[pp ^ 1], m * 16 + br, jj, hq);
            long long rowg = ((long long)(b0 + br) * NBv + (m + 1)) * NVv + v;
            bu_h[rowg * 256 + jj] = f2bf(hn);
            if (v == 0) {
              STA8(Rh[m], br, jj, hq);
              if (m == 0) rc0[p][q] = cn; else rc1[p][q] = cn;
            }
          }
        }
      if (s < CLEN - 1) SWRITE32(Axb[pp ^ 1], xn2);
      STEPSYNC();
    }
  }

  // ================= PHASE 2: bottom-up parent chain (v 63..0) ===============
  {
    *(unsigned long long*)(&Ahb[0][tid * 8]) = 0ull;    // rows 0..15 (4 KB)
    short8 xv; SLOAD16(NVv - 1, xv);
#pragma unroll
    for (int p = 0; p < 2; ++p)
#pragma unroll
      for (int q = 0; q < 4; ++q) c2[0][p][q] = 0.f;
    SWRITE16(Axb[0], xv);
    __syncthreads();
    for (int s = 0; s < NVv; ++s) {
      const int v = NVv - 1 - s, pp = s & 1;
      short8 xn = {};
      if (s < NVv - 1) SLOAD16(v - 1, xn);
      f32x4 acc[1][4][2]; ZACC(1, acc);
      gemm_main8<1>(Wbu, Axb[pp], Ahb[pp], acc, Bp, w, lane);
      const int ck = (v == CI0) ? 0 : ((v == CI1) ? 1 : -1);
      f32x4 accs[4][2]; f32x4 accw[2];
      if (ck >= 0) {
#pragma unroll
        for (int g = 0; g < 4; ++g)
#pragma unroll
          for (int p = 0; p < 2; ++p) accs[g][p] = zf4;
        accw[0] = zf4; accw[1] = zf4;
        const u8* Rp = (ck == 0) ? Rh[0] : Rh[1];
        gemm_side8(Wbu, Wfx, Rp, Axb[pp], accs, accw, w, lane);
      }
#pragma unroll
      for (int p = 0; p < 2; ++p) {
        const int jj = (2 * w + p) * 16 + col;
#pragma unroll
        for (int q = 0; q < 4; ++q) {
          const int br = krow * 4 + q;
          float I  = acc[0][0][p][q] + bi0[p];
          float O  = acc[0][1][p][q] + bi1[p];
          float U  = acc[0][2][p][q] + bi2[p];
          float F1 = acc[0][3][p][q] + bfv[p];
          float fc = sigf(F1) * c2[0][p][q];
          if (ck >= 0) {
            I += accs[0][p][q]; O += accs[1][p][q]; U += accs[2][p][q];
            float wfx = accw[p][q] + bfv[p];
            float rcv = (ck == 0) ? rc0[p][q] : rc1[p][q];
            fc += sigf(wfx + accs[3][p][q]) * rcv;
          }
          float cn = sigf(I) * tanh_f(U) + fc;
          float hn = sigf(O) * tanh_f(cn);
          c2[0][p][q] = cn;
          u8 hq = f2fp8(hn);
          STA8(Ahb[pp ^ 1], br, jj, hq);
          long long rowg = ((long long)(b0 + br) * NBv) * NVv + v;
          bu_h[rowg * 256 + jj] = f2bf(hn);
          if (v == 0) td_h[rowg * 256 + jj] = f2bf(hn);   // td seed
        }
      }
      if (s < NVv - 1) SWRITE16(Axb[pp ^ 1], xn);
      STEPSYNC();
    }
  }
  // phase 2 ended with s=63 (pp=1) -> epilogue wrote Ahb[0]; c2[0] carries.

  // ================= PHASE 3: top-down parent chain (v 1..63) ================
  {
    LOADBP(Wtd);
    short8 xv; SLOAD16(1, xv);
    SWRITE16(Axb[0], xv);
    __syncthreads();
    for (int s = 0; s < NVv - 1; ++s) {
      const int v = 1 + s, pp = s & 1;
      short8 xn = {};
      if (s < NVv - 2) SLOAD16(v + 1, xn);
      f32x4 acc[1][4][2]; ZACC(1, acc);
      gemm_main8<1>(Wtd, Axb[pp], Ahb[pp], acc, Bp, w, lane);
#pragma unroll
      for (int p = 0; p < 2; ++p) {
        const int jj = (2 * w + p) * 16 + col;
#pragma unroll
        for (int q = 0; q < 4; ++q) {
          const int br = krow * 4 + q;
          float I = acc[0][0][p][q] + bt0[p];
          float F = acc[0][1][p][q] + bt1[p];
          float G = acc[0][2][p][q] + bt2[p];
          float O = acc[0][3][p][q] + bt3[p];
          float cn = sigf(F) * c2[0][p][q] + sigf(I) * tanh_f(G);
          float hn = sigf(O) * tanh_f(cn);
          c2[0][p][q] = cn;
          u8 hq = f2fp8(hn);
          STA8(Ahb[pp ^ 1], br, jj, hq);
          long long rowg = ((long long)(b0 + br) * NBv) * NVv + v;
          td_h[rowg * 256 + jj] = f2bf(hn);
          if (v == CI0) { STA8(Rh[0], br, jj, hq); sc0[p][q] = cn; }
          if (v == CI1) { STA8(Rh[1], br, jj, hq); sc1[p][q] = cn; }
        }
      }
      if (s < NVv - 2) SWRITE16(Axb[pp ^ 1], xn);
      STEPSYNC();
    }
  }

  // ================= PHASE 4: fused top-down chains (v 0..39) ================
  {
#pragma unroll
    for (int h_ = 0; h_ < 2; ++h_) {
      int cid = tid + h_ * 512;
      int rr = cid >> 5, ch = cid & 31;
      int mt = rr >> 4, br = rr & 15;
      unsigned long long vv = *(const unsigned long long*)(
          &Rh[mt][0] + (((br * 256 + ch * 8) ^ ((br & 7) << 3))));
      *(unsigned long long*)(&Ahb[0][0] + (((rr * 256 + ch * 8) ^ ((rr & 7) << 3)))) = vv;
    }
    short8 xv2[2]; SLOAD32(0, xv2);
#pragma unroll
    for (int m = 0; m < 2; ++m)
#pragma unroll
      for (int p = 0; p < 2; ++p)
#pragma unroll
        for (int q = 0; q < 4; ++q)
          c2[m][p][q] = (m == 0) ? sc0[p][q] : sc1[p][q];
    SWRITE32(Axb[0], xv2);
    __syncthreads();
    for (int s = 0; s < CLEN; ++s) {
      const int v = s, pp = s & 1;
      short8 xn2[2];
      if (s < CLEN - 1) SLOAD32(v + 1, xn2);
      f32x4 acc[2][4][2]; ZACC(2, acc);
      gemm_main8<2>(Wtd, Axb[pp], Ahb[pp], acc, Bp, w, lane);
#pragma unroll
      for (int m = 0; m < 2; ++m)
#pragma unroll
        for (int p = 0; p < 2; ++p) {
          const int jj = (2 * w + p) * 16 + col;
#pragma unroll
          for (int q = 0; q < 4; ++q) {
            const int br = krow * 4 + q;
            float I = acc[m][0][p][q] + bt0[p];
            float F = acc[m][1][p][q] + bt1[p];
            float G = acc[m][2][p][q] + bt2[p];
            float O = acc[m][3][p][q] + bt3[p];
            float cn = sigf(F) * c2[m][p][q] + sigf(I) * tanh_f(G);
            float hn = sigf(O) * tanh_f(cn);
            c2[m][p][q] = cn;
            u8 hq = f2fp8(hn);
            STA8(Ahb[pp ^ 1], m * 16 + br, jj, hq);
            long long rowg = ((long long)(b0 + br) * NBv + (m + 1)) * NVv + v;
            td_h[rowg * 256 + jj] = f2bf(hn);
          }
        }
      if (s < CLEN - 1) SWRITE32(Axb[pp ^ 1], xn2);
      STEPSYNC();
    }
  }
}

// ================= decoder (round-7 verified) =================================
__global__ __launch_bounds__(256) void dec_kernel(
    const ushort* __restrict__ bu_h, const ushort* __restrict__ td_h,
    const float* __restrict__ cv,
    const ushort* __restrict__ w1p, const float* __restrict__ b1,
    const ushort* __restrict__ w2p, const float* __restrict__ b2,
    float* __restrict__ out)
{
  __shared__ ushort combL[32 * 512];
  __shared__ ushort hidL[32 * 256];
  const long long row0 = (long long)blockIdx.x * 32;
  const int tid = threadIdx.x;

#pragma unroll
  for (int h = 0; h < 8; ++h) {
    int cid = tid + h * 256;
    int rr = cid >> 6, ch = cid & 63;
    long long row = row0 + rr;
    short8 v = (ch < 32)
        ? *(const short8*)(bu_h + row * 256 + ch * 8)
        : *(const short8*)(td_h + row * 256 + (ch - 32) * 8);
    *(short8*)((char*)combL + ((rr * 1024 + ch * 16) ^ ((rr & 7) << 4))) = v;
  }
  __syncthreads();

  const int lane = tid & 63, w = tid >> 6;
  const int col = lane & 15, krow = lane >> 4, kb = krow * 16;
  const f32x4 zf4 = {0.f, 0.f, 0.f, 0.f};
  f32x4 acc[2][4];
#pragma unroll
  for (int m = 0; m < 2; ++m)
#pragma unroll
    for (int g = 0; g < 4; ++g) acc[m][g] = zf4;
#pragma unroll 4
  for (int ks = 0; ks < 16; ++ks) {
    short8 A[2];
#pragma unroll
    for (int m = 0; m < 2; ++m) A[m] = ldA1024(combL, m * 16 + col, ks * 64 + kb);
#pragma unroll
    for (int g = 0; g < 4; ++g) {
      short8 b = *(const short8*)(w1p + ((((w * 4 + g) * 16 + ks) * 64 + lane)) * 8);
#pragma unroll
      for (int m = 0; m < 2; ++m)
        acc[m][g] = __builtin_amdgcn_mfma_f32_16x16x32_bf16(A[m], b, acc[m][g], 0, 0, 0);
    }
  }
#pragma unroll
  for (int g = 0; g < 4; ++g) {
    const int jj = (w * 4 + g) * 16 + col;
    const float bb = b1[jj];
#pragma unroll
    for (int m = 0; m < 2; ++m)
#pragma unroll
      for (int q = 0; q < 4; ++q) {
        ushort hb = f2bf(fmaxf(acc[m][g][q] + bb, 0.f));
        STA(hidL, m * 16 + krow * 4 + q, jj, hb);
      }
  }
  __syncthreads();

  if (w == 0) {
    f32x4 acc2[2]; acc2[0] = zf4; acc2[1] = zf4;
#pragma unroll
    for (int ks = 0; ks < 8; ++ks) {
      short8 bv = *(const short8*)(w2p + ((ks * 64 + lane)) * 8);
#pragma unroll
      for (int m = 0; m < 2; ++m) {
        short8 A = ldA16(hidL, m * 16 + col, ks * 64 + kb);
        acc2[m] = __builtin_amdgcn_mfma_f32_16x16x32_bf16(A, bv, acc2[m], 0, 0, 0);
      }
    }
    if (col < 3) {
      const float bb = b2[col];
#pragma unroll
      for (int m = 0; m < 2; ++m)
#pragma unroll
        for (int q = 0; q < 4; ++q) {
          long long row = row0 + m * 16 + krow * 4 + q;
          int v  = (int)(row & 63);
          int br = (int)((row >> 6) % 3);
          float res = 0.f;
          if (br == 0 || v < CLEN)
            res = cv[row * 3 + col] + acc2[m][q] + bb;
          out[row * 3 + col] = res;
        }
    }
  }
}

extern "C" void kernel_launch(void* const* d_in, const int* in_sizes, int n_in,
                              void* d_out, int out_size, void* d_ws, size_t ws_size,
                              hipStream_t stream) {
  const float* cv     = (const float*)d_in[0];
  const float* pv     = (const float*)d_in[1];
  const float* hints  = (const float*)d_in[2];
  const float* enc_w1 = (const float*)d_in[3];
  const float* enc_b1 = (const float*)d_in[4];
  const float* enc_w2 = (const float*)d_in[5];
  const float* enc_b2 = (const float*)d_in[6];
  const float* W_iou  = (const float*)d_in[7];
  const float* b_iou  = (const float*)d_in[8];
  const float* U_iou  = (const float*)d_in[9];
  const float* W_f    = (const float*)d_in[10];
  const float* b_f    = (const float*)d_in[11];
  const float* U_f    = (const float*)d_in[12];
  const float* W_ih   = (const float*)d_in[13];
  const float* b_ih   = (const float*)d_in[14];
  const float* W_hh   = (const float*)d_in[15];
  const float* b_hh   = (const float*)d_in[16];
  const float* dec_w1 = (const float*)d_in[17];
  const float* dec_b1 = (const float*)d_in[18];
  const float* dec_w2 = (const float*)d_in[19];
  const float* dec_b2 = (const float*)d_in[20];

  size_t act = (size_t)NROWS * 256;
  size_t need = 2 * act * 2                       // encW + buh (bf16)
              + 2 * (size_t)524288 + 65536        // Wbu8 + Wtd8 + Wfx8 (fp8)
              + (65536 + 131072 + 4096) * 2;      // enc/dec bf16 packs
  if (ws_size < need) return;

  ushort* encW   = (ushort*)d_ws;     // enc, overwritten in place as td_h
  ushort* buh    = encW + act;
  u8*     Wbu8   = (u8*)(buh + act);
  u8*     Wtd8   = Wbu8 + 524288;
  u8*     Wfx8   = Wtd8 + 524288;
  ushort* encw2p = (ushort*)(Wfx8 + 65536);
  ushort* decw1p = encw2p + 65536;
  ushort* decw2p = decw1p + 131072;

  pack_bu8_kernel<<<256, 256, 0, stream>>>(W_iou, W_f, U_iou, U_f, Wbu8);
  pack_td8_kernel<<<256, 256, 0, stream>>>(W_ih, W_hh, Wtd8);
  pack_wfx8_kernel<<<32, 256, 0, stream>>>(W_f, Wfx8);
  pack_encw2_kernel<<<256, 256, 0, stream>>>(enc_w2, encw2p);
  pack_decw1_kernel<<<512, 256, 0, stream>>>(dec_w1, decw1p);
  pack_decw2_kernel<<<16, 256, 0, stream>>>(dec_w2, decw2p);

  enc_kernel<<<(int)(NROWS / 32), 256, 0, stream>>>(cv, pv, hints, enc_w1, enc_b1,
                                                    encw2p, enc_b2, encW);
  seq_kernel<<<BATCH / 16, 512, 0, stream>>>(encW, Wbu8, Wtd8, Wfx8, b_iou, b_f,
                                             b_ih, b_hh, buh, encW);
  dec_kernel<<<(int)(NROWS / 32), 256, 0, stream>>>(buh, encW, cv, decw1p, dec_b1,
                                                    decw2p, dec_b2, (float*)d_out);
}

// Round 15
// 1934.895 us; speedup vs baseline: 1.4112x; 1.4112x over previous
//
#include <hip/hip_runtime.h>
#include <hip/hip_bf16.h>
#include <hip/hip_fp8.h>

// BDLOTreeLSTM on MI355X — round 15: REVERT to round-8 kernel verbatim (best:
// 1936us total). R9-R14 explored persistence/barrier/layout variants; all were
// neutral or negative (see session ledger). This is the final configuration.

constexpr int Hd    = 256;
constexpr int NBv   = 3;
constexpr int NVv   = 64;
constexpr int BATCH = 512;
constexpr long long NROWS = (long long)BATCH * NBv * NVv;   // 98304
constexpr int CLEN = 40;
constexpr int CI0 = 16, CI1 = 48;

typedef __hip_bfloat16 bf16;
typedef unsigned short ushort;
typedef unsigned char u8;
typedef __attribute__((ext_vector_type(8))) short short8;
typedef __attribute__((ext_vector_type(4))) float f32x4;
typedef __attribute__((ext_vector_type(2))) long longx2;

__device__ __forceinline__ float sigf(float x)   { return 1.f / (1.f + __expf(-x)); }
__device__ __forceinline__ float tanh_f(float x) { return 1.f - 2.f / (__expf(2.f * x) + 1.f); }

__device__ __forceinline__ ushort f2bf(float x) {
  unsigned u = __float_as_uint(x);
  return (ushort)((u + 0x7FFFu + ((u >> 16) & 1u)) >> 16);   // RNE
}
__device__ __forceinline__ float bf2f(ushort u) {
  return __uint_as_float(((unsigned)u) << 16);
}
__device__ __forceinline__ u8 f2fp8(float x) {
  __hip_fp8_e4m3 q(x);
  return (u8)q.__x;
}

// ================= fp8 weight packing =========================================
// B-frag pair-packed: byte ((nt*(NKS/2)+kp)*64+l)*16 + s*8 + j, ks = kp*2+s.
__global__ __launch_bounds__(256) void pack_bu8_kernel(
    const float* __restrict__ W_iou, const float* __restrict__ W_f,
    const float* __restrict__ U_iou, const float* __restrict__ U_f,
    u8* __restrict__ out)   // [512 K][1024 N]: [[W_iou|W_f];[U_iou|U_f]]
{
  int u = blockIdx.x * 256 + threadIdx.x;      // 0..65535
  int s = u & 1, l = (u >> 1) & 63, T = u >> 7;
  int kp = T & 7, nt = T >> 3;
  int ks = kp * 2 + s;
  int k0 = ks * 32 + (l >> 4) * 8;
  int n  = nt * 16 + (l & 15);
  unsigned long long r = 0;
#pragma unroll
  for (int j = 0; j < 8; ++j) {
    int k = k0 + j;
    float v;
    if (k < 256) v = (n < 768) ? W_iou[k * 768 + n] : W_f[k * 256 + (n - 768)];
    else         v = (n < 768) ? U_iou[(k - 256) * 768 + n] : U_f[(k - 256) * 256 + (n - 768)];
    r |= ((unsigned long long)f2fp8(v)) << (8 * j);
  }
  *(unsigned long long*)(out + (size_t)u * 8) = r;
}

__global__ __launch_bounds__(256) void pack_td8_kernel(
    const float* __restrict__ W_ih, const float* __restrict__ W_hh,
    u8* __restrict__ out)   // [512][1024]: [[W_ih];[W_hh]]
{
  int u = blockIdx.x * 256 + threadIdx.x;
  int s = u & 1, l = (u >> 1) & 63, T = u >> 7;
  int kp = T & 7, nt = T >> 3;
  int ks = kp * 2 + s;
  int k0 = ks * 32 + (l >> 4) * 8;
  int n  = nt * 16 + (l & 15);
  unsigned long long r = 0;
#pragma unroll
  for (int j = 0; j < 8; ++j) {
    int k = k0 + j;
    float v = (k < 256) ? W_ih[k * 1024 + n] : W_hh[(k - 256) * 1024 + n];
    r |= ((unsigned long long)f2fp8(v)) << (8 * j);
  }
  *(unsigned long long*)(out + (size_t)u * 8) = r;
}

__global__ __launch_bounds__(256) void pack_wfx8_kernel(
    const float* __restrict__ W_f, u8* __restrict__ out)   // [256][256], NKS=8
{
  int u = blockIdx.x * 256 + threadIdx.x;      // 0..8191
  int s = u & 1, l = (u >> 1) & 63, T = u >> 7;
  int kp = T & 3, nt = T >> 2;
  int ks = kp * 2 + s;
  int k0 = ks * 32 + (l >> 4) * 8;
  int n  = nt * 16 + (l & 15);
  unsigned long long r = 0;
#pragma unroll
  for (int j = 0; j < 8; ++j)
    r |= ((unsigned long long)f2fp8(W_f[(k0 + j) * 256 + n])) << (8 * j);
  *(unsigned long long*)(out + (size_t)u * 8) = r;
}

// ================= bf16 packs for enc/dec (round-7 verified) ==================
__global__ __launch_bounds__(256) void pack_encw2_kernel(
    const float* __restrict__ w2, ushort* __restrict__ out)   // [256][256], NKS=8
{
  int idx = blockIdx.x * 256 + threadIdx.x;
  int j = idx & 7, l = (idx >> 3) & 63, T = idx >> 9;
  int ks = T & 7, nt = T >> 3;
  int k = ks * 32 + (l >> 4) * 8 + j;
  int n = nt * 16 + (l & 15);
  out[idx] = f2bf(w2[k * 256 + n]);
}

__global__ __launch_bounds__(256) void pack_decw1_kernel(
    const float* __restrict__ w1, ushort* __restrict__ out)   // [512][256], NKS=16
{
  int idx = blockIdx.x * 256 + threadIdx.x;
  int j = idx & 7, l = (idx >> 3) & 63, T = idx >> 9;
  int ks = T & 15, nt = T >> 4;
  int k = ks * 32 + (l >> 4) * 8 + j;
  int n = nt * 16 + (l & 15);
  out[idx] = f2bf(w1[k * 256 + n]);
}

__global__ __launch_bounds__(256) void pack_decw2_kernel(
    const float* __restrict__ w2, ushort* __restrict__ out)   // [256][3->16], NKS=8
{
  int idx = blockIdx.x * 256 + threadIdx.x;
  int j = idx & 7, l = (idx >> 3) & 63, T = idx >> 9;
  int ks = T & 7;
  int k = ks * 32 + (l >> 4) * 8 + j;
  int n = l & 15;
  out[idx] = (n < 3) ? f2bf(w2[k * 3 + n]) : (ushort)0;
}

// ================= LDS helpers ================================================
__device__ __forceinline__ short8 ldA16(const ushort* buf, int row, int kbyte) {
  int off = (row * 512 + kbyte) ^ ((row & 7) << 4);
  return *(const short8*)((const char*)buf + off);
}
__device__ __forceinline__ short8 ldA1024(const ushort* buf, int row, int kbyte) {
  int off = (row * 1024 + kbyte) ^ ((row & 7) << 4);
  return *(const short8*)((const char*)buf + off);
}
#define STA(BUF, R, JJ, BITS) { \
    int off_ = ((R) * 512 + (JJ) * 2) ^ (((R) & 7) << 4); \
    (BUF)[off_ >> 1] = (BITS); }
#define STA8(BUF, R, JJ, B8) { \
    int off_ = ((R) * 256 + (JJ)) ^ (((R) & 7) << 3); \
    (BUF)[off_] = (B8); }

// ================= encoder (round-7 verified) =================================
__global__ __launch_bounds__(256) void enc_kernel(
    const float* __restrict__ cv, const float* __restrict__ pv,
    const float* __restrict__ hints,
    const float* __restrict__ w1, const float* __restrict__ b1,
    const ushort* __restrict__ w2p, const float* __restrict__ b2,
    ushort* __restrict__ enc)
{
  __shared__ float fs[32][10];
  __shared__ ushort h1L[32 * 256];
  const long long row0 = (long long)blockIdx.x * 32;
  const int tid = threadIdx.x;
  if (tid < 96) {
    int r = tid / 3, c = tid % 3;
    long long row = row0 + r;
    float a = cv[row * 3 + c];
    fs[r][c]     = a;
    fs[r][3 + c] = a - pv[row * 3 + c];
    fs[r][6 + c] = hints[row * 3 + c];
  }
  __syncthreads();
  {
    const int j = tid;
    float wc[9];
#pragma unroll
    for (int i = 0; i < 9; ++i) wc[i] = w1[i * 256 + j];
    const float bb = b1[j];
    for (int r = 0; r < 32; ++r) {
      float a = bb;
#pragma unroll
      for (int i = 0; i < 9; ++i) a += fs[r][i] * wc[i];
      ushort hb = f2bf(fmaxf(a, 0.f));
      STA(h1L, r, j, hb);
    }
  }
  __syncthreads();
  const int lane = tid & 63, w = tid >> 6;
  const int col = lane & 15, krow = lane >> 4, kb = krow * 16;
  const f32x4 zf4 = {0.f, 0.f, 0.f, 0.f};
  f32x4 acc[2][4];
#pragma unroll
  for (int m = 0; m < 2; ++m)
#pragma unroll
    for (int g = 0; g < 4; ++g) acc[m][g] = zf4;
#pragma unroll
  for (int ks = 0; ks < 8; ++ks) {
    short8 A[2];
#pragma unroll
    for (int m = 0; m < 2; ++m) A[m] = ldA16(h1L, m * 16 + col, ks * 64 + kb);
#pragma unroll
    for (int g = 0; g < 4; ++g) {
      short8 b = *(const short8*)(w2p + ((((w * 4 + g) * 8 + ks) * 64 + lane)) * 8);
#pragma unroll
      for (int m = 0; m < 2; ++m)
        acc[m][g] = __builtin_amdgcn_mfma_f32_16x16x32_bf16(A[m], b, acc[m][g], 0, 0, 0);
    }
  }
#pragma unroll
  for (int g = 0; g < 4; ++g) {
    const int jj = (w * 4 + g) * 16 + col;
    const float bb = b2[jj];
#pragma unroll
    for (int m = 0; m < 2; ++m)
#pragma unroll
      for (int q = 0; q < 4; ++q) {
        long long row = row0 + m * 16 + krow * 4 + q;
        enc[row * 256 + jj] = f2bf(acc[m][g][q] + bb);
      }
  }
}

// ================= seq kernel: fp8 GEMMs ======================================
// A-tile LDS (fp8): [rows][256 B], swizzle byte ^ ((row&7)<<3).
template<int MT>
__device__ __forceinline__ void gemm_main8(
    const u8* __restrict__ W, const u8* __restrict__ AxL,
    const u8* __restrict__ AhL, f32x4 (&acc)[MT][4], int w, int lane)
{
  const int col = lane & 15;
  const int kb  = (lane >> 4) * 8;
  const int sw  = (col & 7) << 3;
#pragma unroll 4
  for (int kp = 0; kp < 8; ++kp) {
    const u8* Ab = (kp < 4) ? AxL : AhL;
    const int ksl = (kp & 3) * 2;
    long a[MT][2];
#pragma unroll
    for (int m = 0; m < MT; ++m) {
      int base = (m * 16 + col) * 256 + ksl * 32 + kb;
      a[m][0] = *(const long*)(Ab + ((base) ^ sw));
      a[m][1] = *(const long*)(Ab + ((base + 32) ^ sw));
    }
#pragma unroll
    for (int g = 0; g < 4; ++g) {
      longx2 bq = *(const longx2*)(W + ((size_t)(((g * 16 + w) * 8 + kp) * 64 + lane) << 4));
#pragma unroll
      for (int m = 0; m < MT; ++m) {
        acc[m][g] = __builtin_amdgcn_mfma_f32_16x16x32_fp8_fp8(a[m][0], bq[0], acc[m][g], 0, 0, 0);
        acc[m][g] = __builtin_amdgcn_mfma_f32_16x16x32_fp8_fp8(a[m][1], bq[1], acc[m][g], 0, 0, 0);
      }
    }
  }
}

__device__ __forceinline__ void gemm_side8(
    const u8* __restrict__ Wbu, const u8* __restrict__ Wfx,
    const u8* __restrict__ Rhb, const u8* __restrict__ AxL,
    f32x4 (&accs)[4], f32x4& accw, int w, int lane)
{
  const int col = lane & 15;
  const int kb  = (lane >> 4) * 8;
  const int sw  = (col & 7) << 3;
#pragma unroll
  for (int kp = 0; kp < 4; ++kp) {
    const int base = col * 256 + kp * 64 + kb;   // ksl*32 = kp*2*32
    long ar0 = *(const long*)(Rhb + ((base) ^ sw));
    long ar1 = *(const long*)(Rhb + ((base + 32) ^ sw));
#pragma unroll
    for (int g = 0; g < 4; ++g) {
      longx2 bq = *(const longx2*)(Wbu + ((size_t)(((g * 16 + w) * 8 + kp + 4) * 64 + lane) << 4));
      accs[g] = __builtin_amdgcn_mfma_f32_16x16x32_fp8_fp8(ar0, bq[0], accs[g], 0, 0, 0);
      accs[g] = __builtin_amdgcn_mfma_f32_16x16x32_fp8_fp8(ar1, bq[1], accs[g], 0, 0, 0);
    }
    long ax0 = *(const long*)(AxL + ((base) ^ sw));
    long ax1 = *(const long*)(AxL + ((base + 32) ^ sw));
    longx2 bw = *(const longx2*)(Wfx + ((size_t)((w * 4 + kp) * 64 + lane) << 4));
    accw = __builtin_amdgcn_mfma_f32_16x16x32_fp8_fp8(ax0, bw[0], accw, 0, 0, 0);
    accw = __builtin_amdgcn_mfma_f32_16x16x32_fp8_fp8(ax1, bw[1], accw, 0, 0, 0);
  }
}

#define ZACC(MT_, A_) { \
  _Pragma("unroll") for (int m_ = 0; m_ < MT_; ++m_) \
  _Pragma("unroll") for (int g_ = 0; g_ < 4; ++g_) A_[m_][g_] = zf4; }

__global__ __launch_bounds__(1024, 4) void seq_kernel(
    const ushort* enc,                      // aliases td_h -> no __restrict__
    const u8* __restrict__ Wbu, const u8* __restrict__ Wtd,
    const u8* __restrict__ Wfx,
    const float* __restrict__ b_iou, const float* __restrict__ b_f,
    const float* __restrict__ b_ih,  const float* __restrict__ b_hh,
    ushort* __restrict__ bu_h, ushort* td_h)
{
  __shared__ u8 Axb[2][32 * 256];
  __shared__ u8 Ahb[2][32 * 256];
  __shared__ u8 Rh[2][16 * 256];

  const int tid  = threadIdx.x;
  const int lane = tid & 63;
  const int w    = tid >> 6;        // wave 0..15
  const int b0   = blockIdx.x * 16;
  const int col  = lane & 15;
  const int krow = lane >> 4;
  const f32x4 zf4 = {0.f, 0.f, 0.f, 0.f};

  const int jj = w * 16 + col;
  const float bi0 = b_iou[jj], bi1 = b_iou[256 + jj], bi2 = b_iou[512 + jj];
  const float bfv = b_f[jj];
  const float bt0 = b_ih[jj]       + b_hh[jj];
  const float bt1 = b_ih[256 + jj] + b_hh[256 + jj];
  const float bt2 = b_ih[512 + jj] + b_hh[512 + jj];
  const float bt3 = b_ih[768 + jj] + b_hh[768 + jj];

  float c2[2][4];
  float rc0[4], rc1[4];
  float sc0[4], sc1[4];

  // staging: one short8 (8 bf16) per thread -> 8 fp8 bytes. T14 split.
#define SLOAD32(V, XV) { \
    int rr_ = tid >> 5, ch_ = tid & 31; \
    int mt_ = rr_ >> 4, br_ = rr_ & 15; \
    long long rowg_ = ((long long)(b0 + br_) * NBv + (mt_ + 1)) * NVv + (V); \
    XV = *(const short8*)(enc + rowg_ * 256 + ch_ * 8); }

#define SLOAD16(V, XV) if (tid < 512) { \
    int rr_ = tid >> 5, ch_ = tid & 31; \
    long long rowg_ = ((long long)(b0 + rr_) * NBv) * NVv + (V); \
    XV = *(const short8*)(enc + rowg_ * 256 + ch_ * 8); }

#define SWRITE(DST, XV, GUARD) if (GUARD) { \
    int rr_ = tid >> 5, ch_ = tid & 31; \
    unsigned long long r_ = 0; \
    _Pragma("unroll") for (int e_ = 0; e_ < 8; ++e_) \
      r_ |= ((unsigned long long)f2fp8(bf2f((ushort)XV[e_]))) << (8 * e_); \
    *(unsigned long long*)((DST) + (((rr_ * 256 + ch_ * 8) ^ ((rr_ & 7) << 3)))) = r_; }

  // ================= PHASE 1: fused bottom-up chains (v 39..0) ===============
  {
    *(unsigned long long*)(&Ahb[0][tid * 8]) = 0ull;
    short8 xv; SLOAD32(CLEN - 1, xv);
#pragma unroll
    for (int m = 0; m < 2; ++m)
#pragma unroll
      for (int q = 0; q < 4; ++q) c2[m][q] = 0.f;
    SWRITE(Axb[0], xv, true);
    __syncthreads();
    for (int s = 0; s < CLEN; ++s) {
      const int v = CLEN - 1 - s, pp = s & 1;
      short8 xn;
      if (s < CLEN - 1) SLOAD32(v - 1, xn);
      f32x4 acc[2][4]; ZACC(2, acc);
      gemm_main8<2>(Wbu, Axb[pp], Ahb[pp], acc, w, lane);
#pragma unroll
      for (int m = 0; m < 2; ++m)
#pragma unroll
        for (int q = 0; q < 4; ++q) {
          const int br = krow * 4 + q;
          float I = acc[m][0][q] + bi0;
          float O = acc[m][1][q] + bi1;
          float U = acc[m][2][q] + bi2;
          float F = acc[m][3][q] + bfv;
          float cn = sigf(I) * tanh_f(U) + sigf(F) * c2[m][q];
          float hn = sigf(O) * tanh_f(cn);
          c2[m][q] = cn;
          u8 hq = f2fp8(hn);
          STA8(Ahb[pp ^ 1], m * 16 + br, jj, hq);
          long long rowg = ((long long)(b0 + br) * NBv + (m + 1)) * NVv + v;
          bu_h[rowg * 256 + jj] = f2bf(hn);
          if (v == 0) {
            STA8(Rh[m], br, jj, hq);
            if (m == 0) rc0[q] = cn; else rc1[q] = cn;
          }
        }
      if (s < CLEN - 1) SWRITE(Axb[pp ^ 1], xn, true);
      __syncthreads();
    }
  }

  // ================= PHASE 2: bottom-up parent chain (v 63..0) ===============
  {
    if (tid < 512) *(unsigned long long*)(&Ahb[0][tid * 8]) = 0ull;
    short8 xv = {};
    SLOAD16(NVv - 1, xv);
#pragma unroll
    for (int q = 0; q < 4; ++q) c2[0][q] = 0.f;
    SWRITE(Axb[0], xv, (tid < 512));
    __syncthreads();
    for (int s = 0; s < NVv; ++s) {
      const int v = NVv - 1 - s, pp = s & 1;
      short8 xn = {};
      if (s < NVv - 1) SLOAD16(v - 1, xn);
      f32x4 acc[1][4]; ZACC(1, acc);
      gemm_main8<1>(Wbu, Axb[pp], Ahb[pp], acc, w, lane);
      const int ck = (v == CI0) ? 0 : ((v == CI1) ? 1 : -1);
      f32x4 accs[4]; f32x4 accw;
      if (ck >= 0) {
#pragma unroll
        for (int g = 0; g < 4; ++g) accs[g] = zf4;
        accw = zf4;
        const u8* Rp = (ck == 0) ? Rh[0] : Rh[1];
        gemm_side8(Wbu, Wfx, Rp, Axb[pp], accs, accw, w, lane);
      }
#pragma unroll
      for (int q = 0; q < 4; ++q) {
        const int br = krow * 4 + q;
        float I  = acc[0][0][q] + bi0;
        float O  = acc[0][1][q] + bi1;
        float U  = acc[0][2][q] + bi2;
        float F1 = acc[0][3][q] + bfv;
        float fc = sigf(F1) * c2[0][q];
        if (ck >= 0) {
          I += accs[0][q]; O += accs[1][q]; U += accs[2][q];
          float wfx = accw[q] + bfv;
          float rcv = (ck == 0) ? rc0[q] : rc1[q];
          fc += sigf(wfx + accs[3][q]) * rcv;
        }
        float cn = sigf(I) * tanh_f(U) + fc;
        float hn = sigf(O) * tanh_f(cn);
        c2[0][q] = cn;
        u8 hq = f2fp8(hn);
        STA8(Ahb[pp ^ 1], br, jj, hq);
        long long rowg = ((long long)(b0 + br) * NBv) * NVv + v;
        bu_h[rowg * 256 + jj] = f2bf(hn);
        if (v == 0) td_h[rowg * 256 + jj] = f2bf(hn);   // td seed
      }
      if (s < NVv - 1) SWRITE(Axb[pp ^ 1], xn, (tid < 512));
      __syncthreads();
    }
  }
  // phase 2 ended with s=63 (pp=1) -> its epilogue wrote Ahb[0]; c2[0] carries.

  // ================= PHASE 3: top-down parent chain (v 1..63) ================
  {
    short8 xv = {};
    SLOAD16(1, xv);
    SWRITE(Axb[0], xv, (tid < 512));
    __syncthreads();
    for (int s = 0; s < NVv - 1; ++s) {
      const int v = 1 + s, pp = s & 1;
      short8 xn = {};
      if (s < NVv - 2) SLOAD16(v + 1, xn);
      f32x4 acc[1][4]; ZACC(1, acc);
      gemm_main8<1>(Wtd, Axb[pp], Ahb[pp], acc, w, lane);
#pragma unroll
      for (int q = 0; q < 4; ++q) {
        const int br = krow * 4 + q;
        float I = acc[0][0][q] + bt0;
        float F = acc[0][1][q] + bt1;
        float G = acc[0][2][q] + bt2;
        float O = acc[0][3][q] + bt3;
        float cn = sigf(F) * c2[0][q] + sigf(I) * tanh_f(G);
        float hn = sigf(O) * tanh_f(cn);
        c2[0][q] = cn;
        u8 hq = f2fp8(hn);
        STA8(Ahb[pp ^ 1], br, jj, hq);
        long long rowg = ((long long)(b0 + br) * NBv) * NVv + v;
        td_h[rowg * 256 + jj] = f2bf(hn);
        if (v == CI0) { STA8(Rh[0], br, jj, hq); sc0[q] = cn; }
        if (v == CI1) { STA8(Rh[1], br, jj, hq); sc1[q] = cn; }
      }
      if (s < NVv - 2) SWRITE(Axb[pp ^ 1], xn, (tid < 512));
      __syncthreads();
    }
  }

  // ================= PHASE 4: fused top-down chains (v 0..39) ================
  {
    {
      int rr = tid >> 5, ch = tid & 31;
      int mt = rr >> 4, br = rr & 15;
      unsigned long long vv = *(const unsigned long long*)(
          &Rh[mt][0] + (((br * 256 + ch * 8) ^ ((br & 7) << 3))));
      *(unsigned long long*)(&Ahb[0][0] + (((rr * 256 + ch * 8) ^ ((rr & 7) << 3)))) = vv;
    }
    short8 xv; SLOAD32(0, xv);
#pragma unroll
    for (int m = 0; m < 2; ++m)
#pragma unroll
      for (int q = 0; q < 4; ++q)
        c2[m][q] = (m == 0) ? sc0[q] : sc1[q];
    SWRITE(Axb[0], xv, true);
    __syncthreads();
    for (int s = 0; s < CLEN; ++s) {
      const int v = s, pp = s & 1;
      short8 xn;
      if (s < CLEN - 1) SLOAD32(v + 1, xn);
      f32x4 acc[2][4]; ZACC(2, acc);
      gemm_main8<2>(Wtd, Axb[pp], Ahb[pp], acc, w, lane);
#pragma unroll
      for (int m = 0; m < 2; ++m)
#pragma unroll
        for (int q = 0; q < 4; ++q) {
          const int br = krow * 4 + q;
          float I = acc[m][0][q] + bt0;
          float F = acc[m][1][q] + bt1;
          float G = acc[m][2][q] + bt2;
          float O = acc[m][3][q] + bt3;
          float cn = sigf(F) * c2[m][q] + sigf(I) * tanh_f(G);
          float hn = sigf(O) * tanh_f(cn);
          c2[m][q] = cn;
          u8 hq = f2fp8(hn);
          STA8(Ahb[pp ^ 1], m * 16 + br, jj, hq);
          long long rowg = ((long long)(b0 + br) * NBv + (m + 1)) * NVv + v;
          td_h[rowg * 256 + jj] = f2bf(hn);
        }
      if (s < CLEN - 1) SWRITE(Axb[pp ^ 1], xn, true);
      __syncthreads();
    }
  }
}

// ================= decoder (round-7 verified) =================================
__global__ __launch_bounds__(256) void dec_kernel(
    const ushort* __restrict__ bu_h, const ushort* __restrict__ td_h,
    const float* __restrict__ cv,
    const ushort* __restrict__ w1p, const float* __restrict__ b1,
    const ushort* __restrict__ w2p, const float* __restrict__ b2,
    float* __restrict__ out)
{
  __shared__ ushort combL[32 * 512];
  __shared__ ushort hidL[32 * 256];
  const long long row0 = (long long)blockIdx.x * 32;
  const int tid = threadIdx.x;

#pragma unroll
  for (int h = 0; h < 8; ++h) {
    int cid = tid + h * 256;
    int rr = cid >> 6, ch = cid & 63;
    long long row = row0 + rr;
    short8 v = (ch < 32)
        ? *(const short8*)(bu_h + row * 256 + ch * 8)
        : *(const short8*)(td_h + row * 256 + (ch - 32) * 8);
    *(short8*)((char*)combL + ((rr * 1024 + ch * 16) ^ ((rr & 7) << 4))) = v;
  }
  __syncthreads();

  const int lane = tid & 63, w = tid >> 6;
  const int col = lane & 15, krow = lane >> 4, kb = krow * 16;
  const f32x4 zf4 = {0.f, 0.f, 0.f, 0.f};
  f32x4 acc[2][4];
#pragma unroll
  for (int m = 0; m < 2; ++m)
#pragma unroll
    for (int g = 0; g < 4; ++g) acc[m][g] = zf4;
#pragma unroll 4
  for (int ks = 0; ks < 16; ++ks) {
    short8 A[2];
#pragma unroll
    for (int m = 0; m < 2; ++m) A[m] = ldA1024(combL, m * 16 + col, ks * 64 + kb);
#pragma unroll
    for (int g = 0; g < 4; ++g) {
      short8 b = *(const short8*)(w1p + ((((w * 4 + g) * 16 + ks) * 64 + lane)) * 8);
#pragma unroll
      for (int m = 0; m < 2; ++m)
        acc[m][g] = __builtin_amdgcn_mfma_f32_16x16x32_bf16(A[m], b, acc[m][g], 0, 0, 0);
    }
  }
#pragma unroll
  for (int g = 0; g < 4; ++g) {
    const int jj = (w * 4 + g) * 16 + col;
    const float bb = b1[jj];
#pragma unroll
    for (int m = 0; m < 2; ++m)
#pragma unroll
      for (int q = 0; q < 4; ++q) {
        ushort hb = f2bf(fmaxf(acc[m][g][q] + bb, 0.f));
        STA(hidL, m * 16 + krow * 4 + q, jj, hb);
      }
  }
  __syncthreads();

  if (w == 0) {
    f32x4 acc2[2]; acc2[0] = zf4; acc2[1] = zf4;
#pragma unroll
    for (int ks = 0; ks < 8; ++ks) {
      short8 bv = *(const short8*)(w2p + ((ks * 64 + lane)) * 8);
#pragma unroll
      for (int m = 0; m < 2; ++m) {
        short8 A = ldA16(hidL, m * 16 + col, ks * 64 + kb);
        acc2[m] = __builtin_amdgcn_mfma_f32_16x16x32_bf16(A, bv, acc2[m], 0, 0, 0);
      }
    }
    if (col < 3) {
      const float bb = b2[col];
#pragma unroll
      for (int m = 0; m < 2; ++m)
#pragma unroll
        for (int q = 0; q < 4; ++q) {
          long long row = row0 + m * 16 + krow * 4 + q;
          int v  = (int)(row & 63);
          int br = (int)((row >> 6) % 3);
          float res = 0.f;
          if (br == 0 || v < CLEN)
            res = cv[row * 3 + col] + acc2[m][q] + bb;
          out[row * 3 + col] = res;
        }
    }
  }
}

extern "C" void kernel_launch(void* const* d_in, const int* in_sizes, int n_in,
                              void* d_out, int out_size, void* d_ws, size_t ws_size,
                              hipStream_t stream) {
  const float* cv     = (const float*)d_in[0];
  const float* pv     = (const float*)d_in[1];
  const float* hints  = (const float*)d_in[2];
  const float* enc_w1 = (const float*)d_in[3];
  const float* enc_b1 = (const float*)d_in[4];
  const float* enc_w2 = (const float*)d_in[5];
  const float* enc_b2 = (const float*)d_in[6];
  const float* W_iou  = (const float*)d_in[7];
  const float* b_iou  = (const float*)d_in[8];
  const float* U_iou  = (const float*)d_in[9];
  const float* W_f    = (const float*)d_in[10];
  const float* b_f    = (const float*)d_in[11];
  const float* U_f    = (const float*)d_in[12];
  const float* W_ih   = (const float*)d_in[13];
  const float* b_ih   = (const float*)d_in[14];
  const float* W_hh   = (const float*)d_in[15];
  const float* b_hh   = (const float*)d_in[16];
  const float* dec_w1 = (const float*)d_in[17];
  const float* dec_b1 = (const float*)d_in[18];
  const float* dec_w2 = (const float*)d_in[19];
  const float* dec_b2 = (const float*)d_in[20];

  size_t act = (size_t)NROWS * 256;
  size_t need = 2 * act * 2                       // encW + buh (bf16)
              + 2 * (size_t)524288 + 65536        // Wbu8 + Wtd8 + Wfx8 (fp8)
              + (65536 + 131072 + 4096) * 2;      // enc/dec bf16 packs
  if (ws_size < need) return;

  ushort* encW   = (ushort*)d_ws;     // enc, overwritten in place as td_h
  ushort* buh    = encW + act;
  u8*     Wbu8   = (u8*)(buh + act);
  u8*     Wtd8   = Wbu8 + 524288;
  u8*     Wfx8   = Wtd8 + 524288;
  ushort* encw2p = (ushort*)(Wfx8 + 65536);
  ushort* decw1p = encw2p + 65536;
  ushort* decw2p = decw1p + 131072;

  pack_bu8_kernel<<<256, 256, 0, stream>>>(W_iou, W_f, U_iou, U_f, Wbu8);
  pack_td8_kernel<<<256, 256, 0, stream>>>(W_ih, W_hh, Wtd8);
  pack_wfx8_kernel<<<32, 256, 0, stream>>>(W_f, Wfx8);
  pack_encw2_kernel<<<256, 256, 0, stream>>>(enc_w2, encw2p);
  pack_decw1_kernel<<<512, 256, 0, stream>>>(dec_w1, decw1p);
  pack_decw2_kernel<<<16, 256, 0, stream>>>(dec_w2, decw2p);

  enc_kernel<<<(int)(NROWS / 32), 256, 0, stream>>>(cv, pv, hints, enc_w1, enc_b1,
                                                    encw2p, enc_b2, encW);
  seq_kernel<<<BATCH / 16, 1024, 0, stream>>>(encW, Wbu8, Wtd8, Wfx8, b_iou, b_f,
                                              b_ih, b_hh, buh, encW);
  dec_kernel<<<(int)(NROWS / 32), 256, 0, stream>>>(buh, encW, cv, decw1p, dec_b1,
                                                    decw2p, dec_b2, (float*)d_out);
}